// Round 1
// baseline (1667.764 us; speedup 1.0000x reference)
//
#include <hip/hip_runtime.h>
#include <stdint.h>

// ---------------------------------------------------------------------------
// PL_MSA: windowed attention with 2x2 pooled KV, FiLM modulation, rel-pos bias
// DIM=180 HEADS=6 HD=30 N=256 M=64 B=4 NW=256 BW=1024
// Round 1: fp32-accum / fp16-storage vector implementation via v_dot2_f32_f16.
// One block (256 threads) per window; thread t owns token t's row in regs.
// ---------------------------------------------------------------------------

#define NHEADS 6
#define SCALE_Q 0.18257418583505536f  // 30^-0.5

// workspace layout (in 4-byte units):
//   [0,1440)        kvmod fp32: (4 images) x (360)   [scale|shift]
//   [1440,17640)    W_q  fp16x2, pre-scaled by SCALE_Q: 180 rows x 90 dwords
//   [17640,25740)   W_kv fp16x2: 90 rows x 90 dwords
//   [25740,41940)   W_proj fp16x2: 180 rows x 90 dwords
//   [41940,42120)   b_q * SCALE_Q fp32: 180
#define WQ_OFF   1440
#define WKV_OFF  17640
#define WP_OFF   25740
#define BQ_OFF   41940

typedef _Float16 half2v __attribute__((ext_vector_type(2)));

__device__ __forceinline__ float fdot2f(uint32_t a, uint32_t b, float c) {
    return __builtin_amdgcn_fdot2(__builtin_bit_cast(half2v, a),
                                  __builtin_bit_cast(half2v, b), c, false);
}

__device__ __forceinline__ uint32_t pkf16(float lo, float hi) {
    return __builtin_bit_cast(uint32_t, __builtin_amdgcn_cvt_pkrtz(lo, hi));
}

__device__ __forceinline__ unsigned short f16u(float v) {
    return __builtin_bit_cast(unsigned short, (_Float16)v);
}

// 180-element dot product over 90 packed half2 pairs, 4 independent chains.
__device__ __forceinline__ float dot90(const uint32_t* a, const uint32_t* w, float init) {
    float s0 = init, s1 = 0.f, s2 = 0.f, s3 = 0.f;
#pragma unroll
    for (int u = 0; u < 88; u += 4) {
        s0 = fdot2f(a[u + 0], w[u + 0], s0);
        s1 = fdot2f(a[u + 1], w[u + 1], s1);
        s2 = fdot2f(a[u + 2], w[u + 2], s2);
        s3 = fdot2f(a[u + 3], w[u + 3], s3);
    }
    s0 = fdot2f(a[88], w[88], s0);
    s1 = fdot2f(a[89], w[89], s1);
    return (s0 + s1) + (s2 + s3);
}

// ---------------------------------------------------------------------------
// prep: kvmod GEMV (4x360, K=256) + fp16 weight conversion into workspace
// ---------------------------------------------------------------------------
__global__ __launch_bounds__(256) void prep_kernel(
    const float* __restrict__ k_v, const float* __restrict__ W_kernel,
    const float* __restrict__ W_q, const float* __restrict__ b_q,
    const float* __restrict__ W_kv, const float* __restrict__ W_proj,
    float* __restrict__ ws)
{
    const int bid = blockIdx.x, tid = threadIdx.x;
    if (bid < 6) {
        const int j = bid * 256 + tid;           // j = img*360 + o
        if (j < 1440) {
            const int img = j / 360;
            const int o = j - img * 360;
            const float* kr = k_v + img * 256;
            const float* wr = W_kernel + o * 256;
            float s0 = 0.f, s1 = 0.f, s2 = 0.f, s3 = 0.f;
            for (int t = 0; t < 256; t += 4) {
                s0 = fmaf(kr[t + 0], wr[t + 0], s0);
                s1 = fmaf(kr[t + 1], wr[t + 1], s1);
                s2 = fmaf(kr[t + 2], wr[t + 2], s2);
                s3 = fmaf(kr[t + 3], wr[t + 3], s3);
            }
            ws[j] = (s0 + s1) + (s2 + s3);
        }
    } else {
        const int i = (bid - 6) * 256 + tid;
        uint32_t* wsd = (uint32_t*)ws;
        if (i < 16200) {                          // W_q (pre-scaled)
            const int o = i / 90, u = i - o * 90;
            wsd[WQ_OFF + i] = pkf16(W_q[o * 180 + 2 * u] * SCALE_Q,
                                    W_q[o * 180 + 2 * u + 1] * SCALE_Q);
        } else if (i < 24300) {                   // W_kv
            const int k = i - 16200;
            const int o = k / 90, u = k - o * 90;
            wsd[WKV_OFF + k] = pkf16(W_kv[o * 180 + 2 * u],
                                     W_kv[o * 180 + 2 * u + 1]);
        } else if (i < 40500) {                   // W_proj
            const int k = i - 24300;
            const int o = k / 90, u = k - o * 90;
            wsd[WP_OFF + k] = pkf16(W_proj[o * 180 + 2 * u],
                                    W_proj[o * 180 + 2 * u + 1]);
        } else if (i < 40680) {                   // b_q * SCALE
            const int k = i - 40500;
            ws[BQ_OFF + k] = b_q[k] * SCALE_Q;
        }
    }
}

// ---------------------------------------------------------------------------
// main: one block per window
// ---------------------------------------------------------------------------
__global__ __launch_bounds__(256, 2) void msa_main(
    const float* __restrict__ x,
    const float* __restrict__ mask,
    const float* __restrict__ b_kv,
    const float* __restrict__ bias_table,
    const float* __restrict__ b_proj,
    const int* __restrict__ rel_index,
    const float* __restrict__ ws,
    float* __restrict__ out)
{
    __shared__ __attribute__((aligned(16))) unsigned short kls[NHEADS][64][32];  // k[h][m][d], d 30..31 zero
    __shared__ __attribute__((aligned(16))) unsigned short vtls[NHEADS][30][64]; // v^T[h][d][m]
    __shared__ __attribute__((aligned(16))) unsigned short qlds[256][32];        // per-head q rows, d 30..31 zero

    const int tid = threadIdx.x;
    const int win = blockIdx.x;
    const int img = win >> 8;
    const int w   = win & 255;

    const float*    kvm  = ws + img * 360;             // scale[0:180] shift[180:360]
    const uint32_t* wsd  = (const uint32_t*)ws;
    const uint32_t* wq2  = wsd + WQ_OFF;
    const uint32_t* wkv2 = wsd + WKV_OFF;
    const uint32_t* wp2  = wsd + WP_OFF;
    const float*    bqs  = ws + BQ_OFF;

    // zero the d=30,31 pads (read by the 32-wide attn inner loop)
    for (int i = tid; i < NHEADS * 64; i += 256)
        *(uint32_t*)&kls[i >> 6][i & 63][30] = 0u;
    *(uint32_t*)&qlds[tid][30] = 0u;

    // ---- load x row, FiLM-modulate, pack to fp16 pairs (90 dwords in regs)
    uint32_t xq[90];
    {
        const float* xr = x + (size_t)win * (256 * 180) + tid * 180;
#pragma unroll
        for (int u4 = 0; u4 < 45; ++u4) {
            float4 v = *(const float4*)(xr + 4 * u4);
            const int c = 4 * u4;
            float a0 = fmaf(v.x, kvm[c + 0], kvm[180 + c + 0]);
            float a1 = fmaf(v.y, kvm[c + 1], kvm[180 + c + 1]);
            float a2 = fmaf(v.z, kvm[c + 2], kvm[180 + c + 2]);
            float a3 = fmaf(v.w, kvm[c + 3], kvm[180 + c + 3]);
            xq[2 * u4]     = pkf16(a0, a1);
            xq[2 * u4 + 1] = pkf16(a2, a3);
        }
    }

    // ---- kv linear (90 outs, K=180) + pooling scatter into kls/vtls
    {
        const int i1 = tid >> 5, aa = (tid >> 4) & 1, i2 = (tid >> 1) & 7, a2 = tid & 1;
        const int mm   = i1 * 8 + i2;          // pooled token
        const int base = aa * 90 + a2 * 45;    // channel-pack offset within 180

        auto scatter = [&](int j, float acc) {
            const unsigned short hv = f16u(acc);
            const int d45  = (j < 45) ? j : j - 45;
            const int flat = base + d45;
            const int h = flat / 30;
            const int d = flat - h * 30;
            if (j < 45) kls[h][mm][d] = hv;
            else        vtls[h][d][mm] = hv;
        };

        for (int j = 0; j < 90; j += 2) {
            float a0 = dot90(xq, wkv2 + j * 90,       b_kv[j]);
            float a1 = dot90(xq, wkv2 + (j + 1) * 90, b_kv[j + 1]);
            scatter(j, a0);
            scatter(j + 1, a1);
        }
    }
    __syncthreads();

    // ---- per-head attention; attention-out kept packed in osv (static idx)
    uint32_t osv[90];
    const int*   relrow = rel_index + tid * 64;
    const float* mrow   = mask + ((size_t)w * 256 + tid) * 64;

    for (int h = 0; h < NHEADS; ++h) {
        // q_h for own token -> qlds row (own row only; no barrier needed)
        for (int d = 0; d < 30; d += 2) {
            float a0 = dot90(xq, wq2 + (h * 30 + d) * 90,     bqs[h * 30 + d]);
            float a1 = dot90(xq, wq2 + (h * 30 + d + 1) * 90, bqs[h * 30 + d + 1]);
            qlds[tid][d]     = f16u(a0);
            qlds[tid][d + 1] = f16u(a1);
        }

        // logits: s[m] = q.k[m] + bias_table[rel_index[t][m]][h] + mask[w][t][m]
        float sv[64];
#pragma unroll
        for (int m2 = 0; m2 < 64; ++m2)
            sv[m2] = bias_table[relrow[m2] * NHEADS + h] + mrow[m2];

        const uint2* qrow2 = (const uint2*)&qlds[tid][0];
        for (int u2 = 0; u2 < 8; ++u2) {       // covers d 0..31 (pads zeroed)
            const uint2 qq = qrow2[u2];
#pragma unroll
            for (int m2 = 0; m2 < 64; ++m2) {
                const uint2 kk = ((const uint2*)&kls[h][m2][0])[u2];
                sv[m2] = fdot2f(qq.x, kk.x, sv[m2]);
                sv[m2] = fdot2f(qq.y, kk.y, sv[m2]);
            }
        }

        // softmax over m (unnormalized; 1/sum folded into PV output)
        float mx = -3.0e38f;
#pragma unroll
        for (int m2 = 0; m2 < 64; ++m2) mx = fmaxf(mx, sv[m2]);
        float ssum = 0.f;
#pragma unroll
        for (int m2 = 0; m2 < 64; ++m2) {
            float e = __expf(sv[m2] - mx);
            sv[m2] = e;
            ssum += e;
        }
        const float inv = 1.0f / ssum;

        uint32_t P2[32];
#pragma unroll
        for (int u = 0; u < 32; ++u) P2[u] = pkf16(sv[2 * u], sv[2 * u + 1]);

        // PV: out_h[d] = sum_m P[m] * v[m][d]   (v^T rows are m-contiguous)
        float ov[30];
#pragma unroll
        for (int d = 0; d < 30; ++d) {
            const uint2* vrow = (const uint2*)&vtls[h][d][0];
            float s0 = 0.f, s1 = 0.f, s2 = 0.f, s3 = 0.f;
#pragma unroll
            for (int u = 0; u < 16; u += 2) {
                const uint2 va = vrow[u], vb = vrow[u + 1];
                s0 = fdot2f(P2[2 * u + 0], va.x, s0);
                s1 = fdot2f(P2[2 * u + 1], va.y, s1);
                s2 = fdot2f(P2[2 * u + 2], vb.x, s2);
                s3 = fdot2f(P2[2 * u + 3], vb.y, s3);
            }
            ov[d] = ((s0 + s1) + (s2 + s3)) * inv;
        }

        uint32_t op[15];
#pragma unroll
        for (int u = 0; u < 15; ++u) op[u] = pkf16(ov[2 * u], ov[2 * u + 1]);

        if (h == 0) {
#pragma unroll
            for (int u = 0; u < 15; ++u) osv[u] = op[u];
        } else if (h == 1) {
#pragma unroll
            for (int u = 0; u < 15; ++u) osv[15 + u] = op[u];
        } else if (h == 2) {
#pragma unroll
            for (int u = 0; u < 15; ++u) osv[30 + u] = op[u];
        } else if (h == 3) {
#pragma unroll
            for (int u = 0; u < 15; ++u) osv[45 + u] = op[u];
        } else if (h == 4) {
#pragma unroll
            for (int u = 0; u < 15; ++u) osv[60 + u] = op[u];
        } else {
#pragma unroll
            for (int u = 0; u < 15; ++u) osv[75 + u] = op[u];
        }
    }

    // ---- output projection (K=180 over packed attention-out) + bias
    {
        float* orow = out + (size_t)win * (256 * 180) + tid * 180;
        for (int c = 0; c < 180; c += 2) {
            float a0 = dot90(osv, wp2 + c * 90,       b_proj[c]);
            float a1 = dot90(osv, wp2 + (c + 1) * 90, b_proj[c + 1]);
            float2 st; st.x = a0; st.y = a1;
            *(float2*)(orow + c) = st;
        }
    }
}

// ---------------------------------------------------------------------------
extern "C" void kernel_launch(void* const* d_in, const int* in_sizes, int n_in,
                              void* d_out, int out_size, void* d_ws, size_t ws_size,
                              hipStream_t stream)
{
    (void)in_sizes; (void)n_in; (void)out_size; (void)ws_size;
    const float* x          = (const float*)d_in[0];
    const float* k_v        = (const float*)d_in[1];
    const float* mask       = (const float*)d_in[2];
    const float* W_kernel   = (const float*)d_in[3];
    const float* W_q        = (const float*)d_in[4];
    const float* b_q        = (const float*)d_in[5];
    const float* W_kv       = (const float*)d_in[6];
    const float* b_kv       = (const float*)d_in[7];
    const float* bias_table = (const float*)d_in[8];
    const float* W_proj     = (const float*)d_in[9];
    const float* b_proj     = (const float*)d_in[10];
    const int*   rel_index  = (const int*)d_in[11];
    float* ws = (float*)d_ws;

    prep_kernel<<<165, 256, 0, stream>>>(k_v, W_kernel, W_q, b_q, W_kv, W_proj, ws);
    msa_main<<<1024, 256, 0, stream>>>(x, mask, b_kv, bias_table, b_proj,
                                       rel_index, ws, (float*)d_out);
}

// Round 2
// 581.141 us; speedup vs baseline: 2.8698x; 2.8698x over previous
//
#include <hip/hip_runtime.h>
#include <stdint.h>

// ---------------------------------------------------------------------------
// PL_MSA round 2: MFMA GEMMs + slim attention middle.
// DIM=180 HEADS=6 HD=30 N=256 M=64 B=4 NW=256 BW=1024
// Pipeline: prep -> qkv_gemm (MFMA) -> attn_mid -> proj_gemm (MFMA)
// ---------------------------------------------------------------------------

#define NHEADS 6
#define SCALE_Q 0.18257418583505536f  // 30^-0.5

// workspace layout (dword offsets)
#define KVM_OFF   0         // 4 x 360 f32 FiLM scale|shift
#define WCAT_OFF  1440      // [288][192] f16 (rows 0..179 Wq*SCALE, 180..269 Wkv, pad 0)
#define WPROJ_OFF 29088     // [192][192] f16
#define BCAT_OFF  47520     // 288 f32
#define RPB_OFF   47808     // [6][256][64] f32 gathered bias
#define BUF_DW    146112    // byte 584448; buf rows: 262144 x 288 f16 (576B stride)
// buf row: cols 0..179 = q (later overwritten by attnout cols 0..191), 180..269 = kvlin

typedef _Float16 half2v __attribute__((ext_vector_type(2)));
typedef _Float16 f16x8  __attribute__((ext_vector_type(8)));
typedef float    f32x4  __attribute__((ext_vector_type(4)));

__device__ __forceinline__ float fdot2f(uint32_t a, uint32_t b, float c) {
    return __builtin_amdgcn_fdot2(__builtin_bit_cast(half2v, a),
                                  __builtin_bit_cast(half2v, b), c, false);
}
__device__ __forceinline__ uint32_t pkf16(float lo, float hi) {
    return __builtin_bit_cast(uint32_t, __builtin_amdgcn_cvt_pkrtz(lo, hi));
}

// ---------------------------------------------------------------------------
// prep: FiLM GEMV + weight packing + rel-pos bias gather
// ---------------------------------------------------------------------------
__global__ __launch_bounds__(256) void prep_kernel(
    const float* __restrict__ k_v, const float* __restrict__ W_kernel,
    const float* __restrict__ W_q, const float* __restrict__ b_q,
    const float* __restrict__ W_kv, const float* __restrict__ b_kv,
    const float* __restrict__ W_proj, const float* __restrict__ bias_table,
    const int* __restrict__ rel_index, float* __restrict__ ws)
{
    const int bid = blockIdx.x, tid = threadIdx.x;
    uint32_t* wsd = (uint32_t*)ws;
    if (bid < 6) {
        const int j = bid * 256 + tid;
        if (j < 1440) {
            const int img = j / 360;
            const int o = j - img * 360;
            const float* kr = k_v + img * 256;
            const float* wr = W_kernel + o * 256;
            float s0 = 0.f, s1 = 0.f, s2 = 0.f, s3 = 0.f;
            for (int t = 0; t < 256; t += 4) {
                s0 = fmaf(kr[t + 0], wr[t + 0], s0);
                s1 = fmaf(kr[t + 1], wr[t + 1], s1);
                s2 = fmaf(kr[t + 2], wr[t + 2], s2);
                s3 = fmaf(kr[t + 3], wr[t + 3], s3);
            }
            ws[KVM_OFF + j] = (s0 + s1) + (s2 + s3);
        }
    } else if (bid < 114) {                       // Wcat [288][192]
        const int i = (bid - 6) * 256 + tid;
        if (i < 27648) {
            const int j = i / 96, k0 = (i - j * 96) * 2;
            float v0 = 0.f, v1 = 0.f;
            if (j < 180) {
                if (k0 < 180)     v0 = W_q[j * 180 + k0] * SCALE_Q;
                if (k0 + 1 < 180) v1 = W_q[j * 180 + k0 + 1] * SCALE_Q;
            } else if (j < 270) {
                const int jj = j - 180;
                if (k0 < 180)     v0 = W_kv[jj * 180 + k0];
                if (k0 + 1 < 180) v1 = W_kv[jj * 180 + k0 + 1];
            }
            wsd[WCAT_OFF + i] = pkf16(v0, v1);
        }
    } else if (bid < 186) {                       // Wproj [192][192]
        const int i = (bid - 114) * 256 + tid;
        if (i < 18432) {
            const int j = i / 96, k0 = (i - j * 96) * 2;
            float v0 = (j < 180 && k0 < 180)     ? W_proj[j * 180 + k0]     : 0.f;
            float v1 = (j < 180 && k0 + 1 < 180) ? W_proj[j * 180 + k0 + 1] : 0.f;
            wsd[WPROJ_OFF + i] = pkf16(v0, v1);
        }
    } else if (bid == 186) {                      // bcat
        if (tid < 288) {
            float b = 0.f;
            if (tid < 180)      b = b_q[tid] * SCALE_Q;
            else if (tid < 270) b = b_kv[tid - 180];
            ws[BCAT_OFF + tid] = b;
        }
    } else {                                      // rpb [6][256][64]
        const int i = (bid - 187) * 256 + tid;
        if (i < 98304) {
            const int m = i & 63, t = (i >> 6) & 255, h = i >> 14;
            ws[RPB_OFF + i] = bias_table[rel_index[t * 64 + m] * NHEADS + h];
        }
    }
}

// ---------------------------------------------------------------------------
// qkv_gemm: [q | kvlin] = film(x) @ Wcat^T + bcat.  BM=64, BN=288, K=192.
// 256 threads = 4 waves (2M x 2N); wave = 32 rows x 144 cols = 2x9 frags.
// A staged in LDS (computed, XOR-swizzled 16B chunks); B read from global.
// ---------------------------------------------------------------------------
__global__ __launch_bounds__(256, 3) void qkv_gemm(
    const float* __restrict__ x, const float* __restrict__ ws_f,
    _Float16* __restrict__ buf)
{
    __shared__ __attribute__((aligned(16))) char As[64 * 384];
    const int tid = threadIdx.x;
    const int m0 = blockIdx.x * 64;
    const uint32_t* wsd = (const uint32_t*)ws_f;
    const _Float16* wcat = (const _Float16*)(wsd + WCAT_OFF);

    // stage A: film(x)[m0..m0+64), padded to 192 f16 cols
    for (int it = 0; it < 6; ++it) {
        const int idx = it * 256 + tid;          // < 1536
        const int r = idx / 24, c = idx - r * 24;
        const int m = m0 + r;
        const int img = m >> 16;
        const float* kvs = ws_f + KVM_OFF + img * 360;
        const int c0 = c * 8;
        float v[8];
        if (c0 + 8 <= 180) {
            float4 x0 = *(const float4*)(x + (size_t)m * 180 + c0);
            float4 x1 = *(const float4*)(x + (size_t)m * 180 + c0 + 4);
            v[0] = x0.x; v[1] = x0.y; v[2] = x0.z; v[3] = x0.w;
            v[4] = x1.x; v[5] = x1.y; v[6] = x1.z; v[7] = x1.w;
#pragma unroll
            for (int e = 0; e < 8; ++e)
                v[e] = fmaf(v[e], kvs[c0 + e], kvs[180 + c0 + e]);
        } else {
#pragma unroll
            for (int e = 0; e < 8; ++e) {
                const int cc = c0 + e;
                v[e] = (cc < 180) ? fmaf(x[(size_t)m * 180 + cc], kvs[cc], kvs[180 + cc]) : 0.f;
            }
        }
        uint4 pk;
        pk.x = pkf16(v[0], v[1]); pk.y = pkf16(v[2], v[3]);
        pk.z = pkf16(v[4], v[5]); pk.w = pkf16(v[6], v[7]);
        *(uint4*)(As + r * 384 + ((c ^ (r & 7)) << 4)) = pk;
    }
    __syncthreads();

    const int lane = tid & 63, wid = tid >> 6;
    const int wr0 = (wid & 1) * 32;
    const int wc0 = (wid >> 1) * 144;
    const int lr = lane & 15, lk = lane >> 4;

    f32x4 acc[2][9];
#pragma unroll
    for (int a = 0; a < 2; ++a)
#pragma unroll
        for (int b = 0; b < 9; ++b) acc[a][b] = (f32x4){0.f, 0.f, 0.f, 0.f};

#pragma unroll 2
    for (int kk = 0; kk < 6; ++kk) {
        f16x8 bf[9];
#pragma unroll
        for (int nf = 0; nf < 9; ++nf)
            bf[nf] = *(const f16x8*)(wcat + (size_t)(wc0 + nf * 16 + lr) * 192 + kk * 32 + lk * 8);
        f16x8 af[2];
#pragma unroll
        for (int mf = 0; mf < 2; ++mf) {
            const int r = wr0 + mf * 16 + lr;
            af[mf] = *(const f16x8*)(As + r * 384 + (((kk * 4 + lk) ^ (r & 7)) << 4));
        }
#pragma unroll
        for (int mf = 0; mf < 2; ++mf)
#pragma unroll
            for (int nf = 0; nf < 9; ++nf)
                acc[mf][nf] = __builtin_amdgcn_mfma_f32_16x16x32_f16(af[mf], bf[nf], acc[mf][nf], 0, 0, 0);
    }

    const float* bcat = ws_f + BCAT_OFF;
#pragma unroll
    for (int mf = 0; mf < 2; ++mf) {
#pragma unroll
        for (int nf = 0; nf < 9; ++nf) {
            const int j = wc0 + nf * 16 + lr;
            const float bb = bcat[j];
            const int mr = m0 + wr0 + mf * 16 + lk * 4;
#pragma unroll
            for (int rr = 0; rr < 4; ++rr)
                buf[(size_t)(mr + rr) * 288 + j] = (_Float16)(acc[mf][nf][rr] + bb);
        }
    }
}

// ---------------------------------------------------------------------------
// attn_mid: pooling scatter + softmax attention per window.
// Reads q/kvlin from buf, overwrites own rows with attn-out (cols 0..191).
// ---------------------------------------------------------------------------
__global__ __launch_bounds__(256, 3) void attn_mid(
    const float* __restrict__ mask, const float* __restrict__ ws_f,
    _Float16* buf)
{
    __shared__ __attribute__((aligned(16))) unsigned short kls[NHEADS][64][32];
    __shared__ __attribute__((aligned(16))) unsigned short vtls[NHEADS][30][64];

    const int t = threadIdx.x, win = blockIdx.x, w = win & 255;
    const size_t row = (size_t)win * 256 + t;
    uint32_t* rowp = (uint32_t*)buf + row * 144;

    // zero kls pad cols 30..31
    for (int i = t; i < NHEADS * 64; i += 256)
        *(uint32_t*)&kls[i >> 6][i & 63][30] = 0u;

    // kv scatter (verified round-1 index math)
    {
        uint32_t kvd[45];
#pragma unroll
        for (int u = 0; u < 22; ++u)
            *(uint2*)&kvd[2 * u] = *(const uint2*)(rowp + 90 + 2 * u);
        kvd[44] = rowp[134];

        const int i1 = t >> 5, aa = (t >> 4) & 1, i2 = (t >> 1) & 7, a2 = t & 1;
        const int mm = i1 * 8 + i2;
        const int base = aa * 90 + a2 * 45;
#pragma unroll
        for (int j = 0; j < 90; ++j) {
            const unsigned short hv =
                (unsigned short)((j & 1) ? (kvd[j >> 1] >> 16) : (kvd[j >> 1] & 0xffffu));
            const int d45 = (j < 45) ? j : j - 45;
            const int flat = base + d45;
            const int h = flat / 30;
            const int d = flat - h * 30;
            if (j < 45) kls[h][mm][d] = hv;
            else        vtls[h][d][mm] = hv;
        }
    }
    __syncthreads();

    const float* mrow = mask + ((size_t)w * 256 + t) * 64;
    const float* rpb  = ws_f + RPB_OFF;

    for (int h = 0; h < NHEADS; ++h) {
        const float* rrow = rpb + (h * 256 + t) * 64;

        float sv[64];
#pragma unroll
        for (int m4 = 0; m4 < 16; ++m4) {
            float4 mv = *(const float4*)(mrow + 4 * m4);
            float4 rv = *(const float4*)(rrow + 4 * m4);
            sv[4 * m4 + 0] = mv.x + rv.x;
            sv[4 * m4 + 1] = mv.y + rv.y;
            sv[4 * m4 + 2] = mv.z + rv.z;
            sv[4 * m4 + 3] = mv.w + rv.w;
        }

        // QK^T: q read from global (L1-resident row), k from LDS b128 broadcast
        const uint32_t* qg = rowp + h * 15;
        for (int u2 = 0; u2 < 4; ++u2) {
            const uint32_t q0 = qg[4 * u2 + 0];
            const uint32_t q1 = qg[4 * u2 + 1];
            const uint32_t q2 = qg[4 * u2 + 2];
            const uint32_t q3 = (u2 < 3) ? qg[4 * u2 + 3] : 0u;
#pragma unroll
            for (int m2 = 0; m2 < 64; ++m2) {
                const uint4 k4 = *((const uint4*)&kls[h][m2][0] + u2);
                float s = sv[m2];
                s = fdot2f(q0, k4.x, s);
                s = fdot2f(q1, k4.y, s);
                s = fdot2f(q2, k4.z, s);
                s = fdot2f(q3, k4.w, s);
                sv[m2] = s;
            }
        }

        // softmax (unnormalized; 1/sum folded into PV)
        float mx = -3.0e38f;
#pragma unroll
        for (int m2 = 0; m2 < 64; ++m2) mx = fmaxf(mx, sv[m2]);
        float ssum = 0.f;
#pragma unroll
        for (int m2 = 0; m2 < 64; ++m2) {
            const float e = __expf(sv[m2] - mx);
            sv[m2] = e;
            ssum += e;
        }
        const float inv = 1.0f / ssum;

        uint32_t P2[32];
#pragma unroll
        for (int u = 0; u < 32; ++u) P2[u] = pkf16(sv[2 * u], sv[2 * u + 1]);

        float ov[30];
#pragma unroll
        for (int d = 0; d < 30; ++d) {
            const uint4* vrow = (const uint4*)&vtls[h][d][0];
            float s0 = 0.f, s1 = 0.f, s2 = 0.f, s3 = 0.f;
#pragma unroll
            for (int u = 0; u < 8; u += 2) {
                const uint4 va = vrow[u], vb = vrow[u + 1];
                s0 = fdot2f(P2[4 * u + 0], va.x, s0);
                s1 = fdot2f(P2[4 * u + 1], va.y, s1);
                s2 = fdot2f(P2[4 * u + 2], va.z, s2);
                s3 = fdot2f(P2[4 * u + 3], va.w, s3);
                s0 = fdot2f(P2[4 * u + 4], vb.x, s0);
                s1 = fdot2f(P2[4 * u + 5], vb.y, s1);
                s2 = fdot2f(P2[4 * u + 6], vb.z, s2);
                s3 = fdot2f(P2[4 * u + 7], vb.w, s3);
            }
            ov[d] = ((s0 + s1) + (s2 + s3)) * inv;
        }

        // store this head's attn-out slice over own row (q already consumed)
#pragma unroll
        for (int u = 0; u < 15; ++u)
            rowp[h * 15 + u] = pkf16(ov[2 * u], ov[2 * u + 1]);
    }

    // zero pad cols 180..191 for the proj GEMM's K=192 read
#pragma unroll
    for (int u = 0; u < 6; ++u) rowp[90 + u] = 0u;
}

// ---------------------------------------------------------------------------
// proj_gemm: out = attnout @ Wproj^T + b_proj.  BM=64, BN=192, K=192.
// ---------------------------------------------------------------------------
__global__ __launch_bounds__(256, 3) void proj_gemm(
    const float* __restrict__ ws_f, const _Float16* __restrict__ buf,
    const float* __restrict__ b_proj, float* __restrict__ out)
{
    __shared__ __attribute__((aligned(16))) char As[64 * 384];
    const int tid = threadIdx.x;
    const int m0 = blockIdx.x * 64;
    const _Float16* wproj = (const _Float16*)((const uint32_t*)ws_f + WPROJ_OFF);

    for (int it = 0; it < 6; ++it) {
        const int idx = it * 256 + tid;
        const int r = idx / 24, c = idx - r * 24;
        const uint4 v = *(const uint4*)(buf + (size_t)(m0 + r) * 288 + c * 8);
        *(uint4*)(As + r * 384 + ((c ^ (r & 7)) << 4)) = v;
    }
    __syncthreads();

    const int lane = tid & 63, wid = tid >> 6;
    const int wr0 = (wid & 1) * 32;
    const int wc0 = (wid >> 1) * 96;
    const int lr = lane & 15, lk = lane >> 4;

    f32x4 acc[2][6];
#pragma unroll
    for (int a = 0; a < 2; ++a)
#pragma unroll
        for (int b = 0; b < 6; ++b) acc[a][b] = (f32x4){0.f, 0.f, 0.f, 0.f};

#pragma unroll 2
    for (int kk = 0; kk < 6; ++kk) {
        f16x8 bf[6];
#pragma unroll
        for (int nf = 0; nf < 6; ++nf)
            bf[nf] = *(const f16x8*)(wproj + (size_t)(wc0 + nf * 16 + lr) * 192 + kk * 32 + lk * 8);
        f16x8 af[2];
#pragma unroll
        for (int mf = 0; mf < 2; ++mf) {
            const int r = wr0 + mf * 16 + lr;
            af[mf] = *(const f16x8*)(As + r * 384 + (((kk * 4 + lk) ^ (r & 7)) << 4));
        }
#pragma unroll
        for (int mf = 0; mf < 2; ++mf)
#pragma unroll
            for (int nf = 0; nf < 6; ++nf)
                acc[mf][nf] = __builtin_amdgcn_mfma_f32_16x16x32_f16(af[mf], bf[nf], acc[mf][nf], 0, 0, 0);
    }

#pragma unroll
    for (int mf = 0; mf < 2; ++mf) {
#pragma unroll
        for (int nf = 0; nf < 6; ++nf) {
            const int j = wc0 + nf * 16 + lr;
            if (j < 180) {
                const float bb = b_proj[j];
                const int mr = m0 + wr0 + mf * 16 + lk * 4;
#pragma unroll
                for (int rr = 0; rr < 4; ++rr)
                    out[(size_t)(mr + rr) * 180 + j] = acc[mf][nf][rr] + bb;
            }
        }
    }
}

// ---------------------------------------------------------------------------
extern "C" void kernel_launch(void* const* d_in, const int* in_sizes, int n_in,
                              void* d_out, int out_size, void* d_ws, size_t ws_size,
                              hipStream_t stream)
{
    (void)in_sizes; (void)n_in; (void)out_size; (void)ws_size;
    const float* x          = (const float*)d_in[0];
    const float* k_v        = (const float*)d_in[1];
    const float* mask       = (const float*)d_in[2];
    const float* W_kernel   = (const float*)d_in[3];
    const float* W_q        = (const float*)d_in[4];
    const float* b_q        = (const float*)d_in[5];
    const float* W_kv       = (const float*)d_in[6];
    const float* b_kv       = (const float*)d_in[7];
    const float* bias_table = (const float*)d_in[8];
    const float* W_proj     = (const float*)d_in[9];
    const float* b_proj     = (const float*)d_in[10];
    const int*   rel_index  = (const int*)d_in[11];

    float* ws = (float*)d_ws;
    _Float16* buf = (_Float16*)((uint32_t*)d_ws + BUF_DW);

    prep_kernel<<<571, 256, 0, stream>>>(k_v, W_kernel, W_q, b_q, W_kv, b_kv,
                                         W_proj, bias_table, rel_index, ws);
    qkv_gemm<<<4096, 256, 0, stream>>>(x, ws, buf);
    attn_mid<<<1024, 256, 0, stream>>>(mask, ws, buf);
    proj_gemm<<<4096, 256, 0, stream>>>(ws, buf, b_proj, (float*)d_out);
}

// Round 3
// 423.824 us; speedup vs baseline: 3.9350x; 1.3712x over previous
//
#include <hip/hip_runtime.h>
#include <stdint.h>

// ---------------------------------------------------------------------------
// PL_MSA round 3: fused qkv-GEMM + MFMA attention (per-window block), + proj.
// DIM=180 HEADS=6 HD=30 N=256 M=64 B=4 NW=256 BW=1024
// prep -> fused_qkv_attn (1024 x 512thr) -> proj_gemm
// ---------------------------------------------------------------------------

#define NHEADS 6
#define SCALE_Q 0.18257418583505536f  // 30^-0.5

// workspace layout (dword offsets)
#define KVM_OFF   0         // 4 x 360 f32 FiLM scale|shift
#define WCAT_OFF  1440      // [288][192] f16 (rows 0..179 Wq*SCALE, 180..269 Wkv, pad 0)
#define WPROJ_OFF 29088     // [192][192] f16
#define BCAT_OFF  47520     // 288 f32
#define RPB_OFF   47808     // [6][256][64] f32 gathered bias
#define BUF_DW    146112    // byte 584448; buf rows: 262144 x 192 f16 (384B stride)

typedef _Float16 half2v __attribute__((ext_vector_type(2)));
typedef _Float16 f16x8  __attribute__((ext_vector_type(8)));
typedef float    f32x4  __attribute__((ext_vector_type(4)));

__device__ __forceinline__ uint32_t pkf16(float lo, float hi) {
    return __builtin_bit_cast(uint32_t, __builtin_amdgcn_cvt_pkrtz(lo, hi));
}
__device__ __forceinline__ unsigned short f16b(float v) {
    return __builtin_bit_cast(unsigned short, (_Float16)v);
}

// ---------------------------------------------------------------------------
// prep: FiLM GEMV + weight packing + rel-pos bias gather (unchanged, works)
// ---------------------------------------------------------------------------
__global__ __launch_bounds__(256) void prep_kernel(
    const float* __restrict__ k_v, const float* __restrict__ W_kernel,
    const float* __restrict__ W_q, const float* __restrict__ b_q,
    const float* __restrict__ W_kv, const float* __restrict__ b_kv,
    const float* __restrict__ W_proj, const float* __restrict__ bias_table,
    const int* __restrict__ rel_index, float* __restrict__ ws)
{
    const int bid = blockIdx.x, tid = threadIdx.x;
    uint32_t* wsd = (uint32_t*)ws;
    if (bid < 6) {
        const int j = bid * 256 + tid;
        if (j < 1440) {
            const int img = j / 360;
            const int o = j - img * 360;
            const float* kr = k_v + img * 256;
            const float* wr = W_kernel + o * 256;
            float s0 = 0.f, s1 = 0.f, s2 = 0.f, s3 = 0.f;
            for (int t = 0; t < 256; t += 4) {
                s0 = fmaf(kr[t + 0], wr[t + 0], s0);
                s1 = fmaf(kr[t + 1], wr[t + 1], s1);
                s2 = fmaf(kr[t + 2], wr[t + 2], s2);
                s3 = fmaf(kr[t + 3], wr[t + 3], s3);
            }
            ws[KVM_OFF + j] = (s0 + s1) + (s2 + s3);
        }
    } else if (bid < 114) {                       // Wcat [288][192]
        const int i = (bid - 6) * 256 + tid;
        if (i < 27648) {
            const int j = i / 96, k0 = (i - j * 96) * 2;
            float v0 = 0.f, v1 = 0.f;
            if (j < 180) {
                if (k0 < 180)     v0 = W_q[j * 180 + k0] * SCALE_Q;
                if (k0 + 1 < 180) v1 = W_q[j * 180 + k0 + 1] * SCALE_Q;
            } else if (j < 270) {
                const int jj = j - 180;
                if (k0 < 180)     v0 = W_kv[jj * 180 + k0];
                if (k0 + 1 < 180) v1 = W_kv[jj * 180 + k0 + 1];
            }
            wsd[WCAT_OFF + i] = pkf16(v0, v1);
        }
    } else if (bid < 186) {                       // Wproj [192][192]
        const int i = (bid - 114) * 256 + tid;
        if (i < 18432) {
            const int j = i / 96, k0 = (i - j * 96) * 2;
            float v0 = (j < 180 && k0 < 180)     ? W_proj[j * 180 + k0]     : 0.f;
            float v1 = (j < 180 && k0 + 1 < 180) ? W_proj[j * 180 + k0 + 1] : 0.f;
            wsd[WPROJ_OFF + i] = pkf16(v0, v1);
        }
    } else if (bid == 186) {                      // bcat
        if (tid < 288) {
            float b = 0.f;
            if (tid < 180)      b = b_q[tid] * SCALE_Q;
            else if (tid < 270) b = b_kv[tid - 180];
            ws[BCAT_OFF + tid] = b;
        }
    } else {                                      // rpb [6][256][64]
        const int i = (bid - 187) * 256 + tid;
        if (i < 98304) {
            const int m = i & 63, t = (i >> 6) & 255, h = i >> 14;
            ws[RPB_OFF + i] = bias_table[rel_index[t * 64 + m] * NHEADS + h];
        }
    }
}

// ---------------------------------------------------------------------------
// fused_qkv_attn: per-window block (512 thr = 8 waves, one wave = 32 rows).
//   phase1: [q|kvlin] = film(x) @ Wcat^T + bcat  (MFMA, A-tile in LDS)
//   kv pooling scatter -> Kls/Vt LDS; q kept in accumulator registers
//   attention per head: QK^T (MFMA) + softmax (shfl) + PV (MFMA via P LDS)
//   writes attnout f16 rows (192-wide) to buf
// ---------------------------------------------------------------------------
__global__ __launch_bounds__(512, 2) void fused_qkv_attn(
    const float* __restrict__ x, const float* __restrict__ mask,
    const float* __restrict__ ws_f, _Float16* __restrict__ buf)
{
    __shared__ __attribute__((aligned(16))) char As[98304];   // [256][24 swz 16B chunks]
    __shared__ __attribute__((aligned(16))) char Kls[24576];  // [6][64 m][32 d] swz
    __shared__ __attribute__((aligned(16))) char Vt[24576];   // [6][32 d][64 m] swz

    const int tid = threadIdx.x;
    const int win = blockIdx.x;
    const int img = win >> 8;
    const int w   = win & 255;
    const int lane = tid & 63, wv = tid >> 6;
    const int lr = lane & 15, lk = lane >> 4;
    const int wrow = wv * 32;

    const uint32_t* wsd = (const uint32_t*)ws_f;
    const _Float16* wcat = (const _Float16*)(wsd + WCAT_OFF);
    const float*    kvs  = ws_f + KVM_OFF + img * 360;

    // ---- phase 0: stage film(x) A-tile + zero Kls d-pads
    for (int it = 0; it < 12; ++it) {
        const int idx = it * 512 + tid;          // 0..6143
        const int r = idx / 24, c = idx - r * 24;
        const float* xr = x + ((size_t)win * 256 + r) * 180;
        const int c0 = c * 8;
        float v[8];
        if (c0 + 8 <= 180) {
            float4 x0 = *(const float4*)(xr + c0);
            float4 x1 = *(const float4*)(xr + c0 + 4);
            v[0] = x0.x; v[1] = x0.y; v[2] = x0.z; v[3] = x0.w;
            v[4] = x1.x; v[5] = x1.y; v[6] = x1.z; v[7] = x1.w;
#pragma unroll
            for (int e = 0; e < 8; ++e)
                v[e] = fmaf(v[e], kvs[c0 + e], kvs[180 + c0 + e]);
        } else {
#pragma unroll
            for (int e = 0; e < 8; ++e) {
                const int cc = c0 + e;
                v[e] = (cc < 180) ? fmaf(xr[cc], kvs[cc], kvs[180 + cc]) : 0.f;
            }
        }
        uint4 pk;
        pk.x = pkf16(v[0], v[1]); pk.y = pkf16(v[2], v[3]);
        pk.z = pkf16(v[4], v[5]); pk.w = pkf16(v[6], v[7]);
        *(uint4*)(As + r * 384 + ((c ^ (r & 7)) << 4)) = pk;
    }
    if (tid < 384) {  // Kls[h][m][30..32) = 0
        const int h = tid >> 6, mm = tid & 63;
        *(uint32_t*)(Kls + h * 2048 + mm * 64 + ((3 ^ ((mm >> 1) & 3)) << 4) + 12) = 0u;
    }
    __syncthreads();

    const float* bcat = ws_f + BCAT_OFF;

    // ---- phase 1a: grp1 (cols 144..288) first, so kv accs die early
    f32x4 acc1[2][9];
#pragma unroll
    for (int a = 0; a < 2; ++a)
#pragma unroll
        for (int b = 0; b < 9; ++b) acc1[a][b] = (f32x4){0.f, 0.f, 0.f, 0.f};
    for (int kk = 0; kk < 6; ++kk) {
        f16x8 bf[9];
#pragma unroll
        for (int nf = 0; nf < 9; ++nf)
            bf[nf] = *(const f16x8*)(wcat + (size_t)(144 + nf * 16 + lr) * 192 + kk * 32 + lk * 8);
        f16x8 af[2];
#pragma unroll
        for (int mf = 0; mf < 2; ++mf) {
            const int r = wrow + mf * 16 + lr;
            af[mf] = *(const f16x8*)(As + r * 384 + (((kk * 4 + lk) ^ (r & 7)) << 4));
        }
#pragma unroll
        for (int mf = 0; mf < 2; ++mf)
#pragma unroll
            for (int nf = 0; nf < 9; ++nf)
                acc1[mf][nf] = __builtin_amdgcn_mfma_f32_16x16x32_f16(af[mf], bf[nf], acc1[mf][nf], 0, 0, 0);
    }
#pragma unroll
    for (int nf = 0; nf < 9; ++nf) {
        const float bb = bcat[144 + nf * 16 + lr];
#pragma unroll
        for (int mf = 0; mf < 2; ++mf)
#pragma unroll
            for (int rr = 0; rr < 4; ++rr) acc1[mf][nf][rr] += bb;
    }

    // kv pooling scatter into Kls/Vt (j = col-180 in [0,90))
#pragma unroll
    for (int mf = 0; mf < 2; ++mf)
#pragma unroll
        for (int nf = 2; nf < 8; ++nf)
#pragma unroll
            for (int rr = 0; rr < 4; ++rr) {
                const int j = 144 + nf * 16 + lr - 180;
                if (j >= 0 && j < 90) {
                    const int t = wrow + mf * 16 + lk * 4 + rr;
                    const int i1 = t >> 5, aa = (t >> 4) & 1, i2 = (t >> 1) & 7, a2 = t & 1;
                    const int mm = i1 * 8 + i2;
                    const int base = aa * 90 + a2 * 45;
                    const int d45 = (j < 45) ? j : j - 45;
                    const int flat = base + d45;
                    const int h = (flat * 2185) >> 16;
                    const int d = flat - h * 30;
                    const unsigned short hv = f16b(acc1[mf][nf][rr]);
                    if (j < 45)
                        *(unsigned short*)(Kls + h * 2048 + mm * 64 +
                            ((((unsigned)d >> 3) ^ ((mm >> 1) & 3)) << 4) + (d & 7) * 2) = hv;
                    else
                        *(unsigned short*)(Vt + h * 4096 + d * 128 +
                            ((((unsigned)mm >> 3) ^ (d & 7)) << 4) + (mm & 7) * 2) = hv;
                }
            }

    // zero buf pad cols 180..192 for this wave's rows
    {
        uint32_t* bufd = (uint32_t*)buf;
#pragma unroll
        for (int z = 0; z < 3; ++z) {
            const int idx = z * 64 + lane;       // < 192
            const int r = idx / 6, c = idx - r * 6;
            bufd[((size_t)win * 256 + wrow + r) * 96 + 90 + c] = 0u;
        }
    }

    // ---- phase 1b: grp0 (cols 0..144) — persists as q through attention
    f32x4 acc0[2][9];
#pragma unroll
    for (int a = 0; a < 2; ++a)
#pragma unroll
        for (int b = 0; b < 9; ++b) acc0[a][b] = (f32x4){0.f, 0.f, 0.f, 0.f};
    for (int kk = 0; kk < 6; ++kk) {
        f16x8 bf[9];
#pragma unroll
        for (int nf = 0; nf < 9; ++nf)
            bf[nf] = *(const f16x8*)(wcat + (size_t)(nf * 16 + lr) * 192 + kk * 32 + lk * 8);
        f16x8 af[2];
#pragma unroll
        for (int mf = 0; mf < 2; ++mf) {
            const int r = wrow + mf * 16 + lr;
            af[mf] = *(const f16x8*)(As + r * 384 + (((kk * 4 + lk) ^ (r & 7)) << 4));
        }
#pragma unroll
        for (int mf = 0; mf < 2; ++mf)
#pragma unroll
            for (int nf = 0; nf < 9; ++nf)
                acc0[mf][nf] = __builtin_amdgcn_mfma_f32_16x16x32_f16(af[mf], bf[nf], acc0[mf][nf], 0, 0, 0);
    }
#pragma unroll
    for (int nf = 0; nf < 9; ++nf) {
        const float bb = bcat[nf * 16 + lr];
#pragma unroll
        for (int mf = 0; mf < 2; ++mf)
#pragma unroll
            for (int rr = 0; rr < 4; ++rr) acc0[mf][nf][rr] += bb;
    }
    __syncthreads();   // Kls/Vt complete; As dead -> reuse for qsc/P

    char* qscW = As + wv * 2048;             // [32][32] f16, chunk swz c^((r>>1)&3)
    char* PW   = As + 16384 + wv * 4096;     // [32][64] f16, chunk swz c^(r&7)
    if (lane < 32)  // zero qsc d-pads 30..31
        *(uint32_t*)(qscW + lane * 64 + ((3 ^ ((lane >> 1) & 3)) << 4) + 12) = 0u;

    const float* rpb0 = ws_f + RPB_OFF;

#pragma unroll
    for (int h = 0; h < NHEADS; ++h) {
        // write this head's q slice [32 rows][d<30] to wave scratch
#pragma unroll
        for (int pf = 0; pf < 12; ++pf) {
            const int colbase = pf * 16;
            if (colbase + 16 > 30 * h && colbase < 30 * h + 30) {
#pragma unroll
                for (int mf = 0; mf < 2; ++mf)
#pragma unroll
                    for (int rr = 0; rr < 4; ++rr) {
                        const int d = colbase + lr - 30 * h;
                        if (d >= 0 && d < 30) {
                            const float qv = (pf < 9) ? acc0[mf][pf][rr] : acc1[mf][pf - 9][rr];
                            const int rL = mf * 16 + lk * 4 + rr;
                            *(unsigned short*)(qscW + rL * 64 +
                                ((((unsigned)d >> 3) ^ ((rL >> 1) & 3)) << 4) + (d & 7) * 2) = f16b(qv);
                        }
                    }
            }
        }

        // QK^T
        f16x8 qf[2], kf[4];
#pragma unroll
        for (int qt = 0; qt < 2; ++qt) {
            const int rL = qt * 16 + lr;
            qf[qt] = *(const f16x8*)(qscW + rL * 64 + ((lk ^ ((rL >> 1) & 3)) << 4));
        }
#pragma unroll
        for (int mt = 0; mt < 4; ++mt) {
            const int mm = mt * 16 + lr;
            kf[mt] = *(const f16x8*)(Kls + h * 2048 + mm * 64 + ((lk ^ ((mm >> 1) & 3)) << 4));
        }
        f32x4 sa[2][4];
        const float* rpb = rpb0 + (h << 14);
#pragma unroll
        for (int qt = 0; qt < 2; ++qt)
#pragma unroll
            for (int mt = 0; mt < 4; ++mt)
#pragma unroll
                for (int rr = 0; rr < 4; ++rr) {
                    const int t = wrow + qt * 16 + lk * 4 + rr;
                    const int m = mt * 16 + lr;
                    sa[qt][mt][rr] = rpb[(t << 6) + m] + mask[(((w << 8) + t) << 6) + m];
                }
#pragma unroll
        for (int qt = 0; qt < 2; ++qt)
#pragma unroll
            for (int mt = 0; mt < 4; ++mt)
                sa[qt][mt] = __builtin_amdgcn_mfma_f32_16x16x32_f16(qf[qt], kf[mt], sa[qt][mt], 0, 0, 0);

        // softmax over m (16 lanes x 4 frags), unnormalized P
        float invv[2][4];
#pragma unroll
        for (int qt = 0; qt < 2; ++qt) {
            float mx[4], sm[4];
#pragma unroll
            for (int rr = 0; rr < 4; ++rr)
                mx[rr] = fmaxf(fmaxf(sa[qt][0][rr], sa[qt][1][rr]),
                               fmaxf(sa[qt][2][rr], sa[qt][3][rr]));
#pragma unroll
            for (int xm = 1; xm < 16; xm <<= 1)
#pragma unroll
                for (int rr = 0; rr < 4; ++rr)
                    mx[rr] = fmaxf(mx[rr], __shfl_xor(mx[rr], xm));
#pragma unroll
            for (int mt = 0; mt < 4; ++mt)
#pragma unroll
                for (int rr = 0; rr < 4; ++rr)
                    sa[qt][mt][rr] = __expf(sa[qt][mt][rr] - mx[rr]);
#pragma unroll
            for (int rr = 0; rr < 4; ++rr)
                sm[rr] = (sa[qt][0][rr] + sa[qt][1][rr]) + (sa[qt][2][rr] + sa[qt][3][rr]);
#pragma unroll
            for (int xm = 1; xm < 16; xm <<= 1)
#pragma unroll
                for (int rr = 0; rr < 4; ++rr)
                    sm[rr] += __shfl_xor(sm[rr], xm);
#pragma unroll
            for (int rr = 0; rr < 4; ++rr) invv[qt][rr] = 1.0f / sm[rr];
            // store P
#pragma unroll
            for (int mt = 0; mt < 4; ++mt)
#pragma unroll
                for (int rr = 0; rr < 4; ++rr) {
                    const int rL = qt * 16 + lk * 4 + rr;
                    const int m = mt * 16 + lr;
                    *(unsigned short*)(PW + rL * 128 +
                        ((((unsigned)m >> 3) ^ (rL & 7)) << 4) + (m & 7) * 2) = f16b(sa[qt][mt][rr]);
                }
        }

        // PV
        f32x4 oa[2][2];
#pragma unroll
        for (int a = 0; a < 2; ++a)
#pragma unroll
            for (int b = 0; b < 2; ++b) oa[a][b] = (f32x4){0.f, 0.f, 0.f, 0.f};
#pragma unroll
        for (int ks = 0; ks < 2; ++ks) {
            f16x8 pa[2], vb[2];
#pragma unroll
            for (int qt = 0; qt < 2; ++qt) {
                const int rL = qt * 16 + lr;
                pa[qt] = *(const f16x8*)(PW + rL * 128 + (((ks * 4 + lk) ^ (rL & 7)) << 4));
            }
#pragma unroll
            for (int df = 0; df < 2; ++df) {
                const int d = df * 16 + lr;
                vb[df] = *(const f16x8*)(Vt + h * 4096 + d * 128 + (((ks * 4 + lk) ^ (d & 7)) << 4));
            }
#pragma unroll
            for (int qt = 0; qt < 2; ++qt)
#pragma unroll
                for (int df = 0; df < 2; ++df)
                    oa[qt][df] = __builtin_amdgcn_mfma_f32_16x16x32_f16(pa[qt], vb[df], oa[qt][df], 0, 0, 0);
        }

        // O write (normalized) -> buf
#pragma unroll
        for (int qt = 0; qt < 2; ++qt)
#pragma unroll
            for (int df = 0; df < 2; ++df)
#pragma unroll
                for (int rr = 0; rr < 4; ++rr) {
                    const int d = df * 16 + lr;
                    if (d < 30) {
                        const float v = oa[qt][df][rr] * invv[qt][rr];
                        const size_t row = (size_t)win * 256 + wrow + qt * 16 + lk * 4 + rr;
                        buf[row * 192 + h * 30 + d] = (_Float16)v;
                    }
                }
    }
}

// ---------------------------------------------------------------------------
// proj_gemm: out = attnout @ Wproj^T + b_proj.  BM=64, BN=192, K=192.
// ---------------------------------------------------------------------------
__global__ __launch_bounds__(256, 3) void proj_gemm(
    const float* __restrict__ ws_f, const _Float16* __restrict__ buf,
    const float* __restrict__ b_proj, float* __restrict__ out)
{
    __shared__ __attribute__((aligned(16))) char As[64 * 384];
    const int tid = threadIdx.x;
    const int m0 = blockIdx.x * 64;
    const _Float16* wproj = (const _Float16*)((const uint32_t*)ws_f + WPROJ_OFF);

    for (int it = 0; it < 6; ++it) {
        const int idx = it * 256 + tid;
        const int r = idx / 24, c = idx - r * 24;
        const uint4 v = *(const uint4*)(buf + (size_t)(m0 + r) * 192 + c * 8);
        *(uint4*)(As + r * 384 + ((c ^ (r & 7)) << 4)) = v;
    }
    __syncthreads();

    const int lane = tid & 63, wid = tid >> 6;
    const int wr0 = (wid & 1) * 32;
    const int wc0 = (wid >> 1) * 96;
    const int lr = lane & 15, lk = lane >> 4;

    f32x4 acc[2][6];
#pragma unroll
    for (int a = 0; a < 2; ++a)
#pragma unroll
        for (int b = 0; b < 6; ++b) acc[a][b] = (f32x4){0.f, 0.f, 0.f, 0.f};

#pragma unroll 2
    for (int kk = 0; kk < 6; ++kk) {
        f16x8 bf[6];
#pragma unroll
        for (int nf = 0; nf < 6; ++nf)
            bf[nf] = *(const f16x8*)(wproj + (size_t)(wc0 + nf * 16 + lr) * 192 + kk * 32 + lk * 8);
        f16x8 af[2];
#pragma unroll
        for (int mf = 0; mf < 2; ++mf) {
            const int r = wr0 + mf * 16 + lr;
            af[mf] = *(const f16x8*)(As + r * 384 + (((kk * 4 + lk) ^ (r & 7)) << 4));
        }
#pragma unroll
        for (int mf = 0; mf < 2; ++mf)
#pragma unroll
            for (int nf = 0; nf < 6; ++nf)
                acc[mf][nf] = __builtin_amdgcn_mfma_f32_16x16x32_f16(af[mf], bf[nf], acc[mf][nf], 0, 0, 0);
    }

#pragma unroll
    for (int mf = 0; mf < 2; ++mf) {
#pragma unroll
        for (int nf = 0; nf < 6; ++nf) {
            const int j = wc0 + nf * 16 + lr;
            if (j < 180) {
                const float bb = b_proj[j];
                const int mr = m0 + wr0 + mf * 16 + lk * 4;
#pragma unroll
                for (int rr = 0; rr < 4; ++rr)
                    out[(size_t)(mr + rr) * 180 + j] = acc[mf][nf][rr] + bb;
            }
        }
    }
}

// ---------------------------------------------------------------------------
extern "C" void kernel_launch(void* const* d_in, const int* in_sizes, int n_in,
                              void* d_out, int out_size, void* d_ws, size_t ws_size,
                              hipStream_t stream)
{
    (void)in_sizes; (void)n_in; (void)out_size; (void)ws_size;
    const float* x          = (const float*)d_in[0];
    const float* k_v        = (const float*)d_in[1];
    const float* mask       = (const float*)d_in[2];
    const float* W_kernel   = (const float*)d_in[3];
    const float* W_q        = (const float*)d_in[4];
    const float* b_q        = (const float*)d_in[5];
    const float* W_kv       = (const float*)d_in[6];
    const float* b_kv       = (const float*)d_in[7];
    const float* bias_table = (const float*)d_in[8];
    const float* W_proj     = (const float*)d_in[9];
    const float* b_proj     = (const float*)d_in[10];
    const int*   rel_index  = (const int*)d_in[11];

    float* ws = (float*)d_ws;
    _Float16* buf = (_Float16*)((uint32_t*)d_ws + BUF_DW);

    prep_kernel<<<571, 256, 0, stream>>>(k_v, W_kernel, W_q, b_q, W_kv, b_kv,
                                         W_proj, bias_table, rel_index, ws);
    fused_qkv_attn<<<1024, 512, 0, stream>>>(x, mask, ws, buf);
    proj_gemm<<<4096, 256, 0, stream>>>(ws, buf, b_proj, (float*)d_out);
}